// Round 3
// baseline (244.773 us; speedup 1.0000x reference)
//
#include <hip/hip_runtime.h>
#include <math.h>

#define WAVE_LDS_FENCE() asm volatile("s_waitcnt lgkmcnt(0)" ::: "memory")

constexpr int Cc = 64;
constexpr int Nn = 16384;
constexpr int Ss = 16;
constexpr int WAVES = 4;   // waves per block
constexpr int PTS = 8;     // consecutive points per wave

// ---- DPP helpers (pure VALU cross-lane) ----
template <int CTRL>
__device__ __forceinline__ float dpp_f(float x) {
    return __int_as_float(
        __builtin_amdgcn_update_dpp(0, __float_as_int(x), CTRL, 0xF, 0xF, false));
}
// row_ror chain: every lane of each 16-lane row gets the row sum / max
__device__ __forceinline__ float rsum16(float v) {
    v += dpp_f<0x128>(v); v += dpp_f<0x124>(v);
    v += dpp_f<0x122>(v); v += dpp_f<0x121>(v);
    return v;
}
__device__ __forceinline__ float rmax16(float v) {
    v = fmaxf(v, dpp_f<0x128>(v)); v = fmaxf(v, dpp_f<0x124>(v));
    v = fmaxf(v, dpp_f<0x122>(v)); v = fmaxf(v, dpp_f<0x121>(v));
    return v;
}
__device__ __forceinline__ float lanebc(float v, int l) {
    return __int_as_float(__builtin_amdgcn_readlane(__float_as_int(v), l));
}
// full 64-lane sum in all lanes: 6 DPP + 1 readlane, ZERO DS ops
__device__ __forceinline__ float sum64(float v) {
    v = rsum16(v);
    v += dpp_f<0x142>(v);   // row_bcast15: lane15 -> 16..31, lane47 -> 48..63
    v += dpp_f<0x143>(v);   // row_bcast31: lane31 -> 32..63
    return lanebc(v, 63);   // lane 63 holds the full sum
}

__global__ __launch_bounds__(256, 2) void pt_attn_kernel(
    const float* __restrict__ xyz,      // [B,3,N]
    const float* __restrict__ nxyz,     // [B,3,N,S]
    const float* __restrict__ points,   // [B,C,N]
    const float* __restrict__ npts,     // [B,C,N,S]
    const float* __restrict__ Wk,       // [C,C]
    const float* __restrict__ Wv,       // [64,C+3]
    const float* __restrict__ Wp,       // [C,4]
    float* __restrict__ out)            // [B,64,N]
{
    __shared__ float np_lds[WAVES][64 * 17];          // stride-17 rows: conflict-free rows & cols
    __shared__ __align__(16) float q_lds[WAVES][64];
    __shared__ __align__(16) float qk_lds[WAVES][64];

    const int tid = threadIdx.x;
    const int w = tid >> 6;
    const int lane = tid & 63;
    const int s = lane & 15;
    const int g = lane >> 4;

    // ---- per-lane weights (register-resident, block-persistent) ----
    float wk[64];   // Wk column `lane`
#pragma unroll
    for (int o = 0; o < 64; ++o) wk[o] = Wk[o * 64 + lane];
    float wv[67];   // Wv row `lane`
#pragma unroll
    for (int j = 0; j < 67; ++j) wv[j] = Wv[lane * 67 + j];
    const float4 wp = ((const float4*)Wp)[lane];
    // bp dropped: constant-in-s logit shift cancels in softmax

    const int pt0 = blockIdx.x * (WAVES * PTS) + w * PTS;
    const int b = pt0 >> 14;
    const int n0 = pt0 & (Nn - 1);

    const float* nprow = npts + ((size_t)(b * Cc + lane) * Nn + n0) * Ss;
    const float* qrow  = points + (size_t)(b * Cc + lane) * Nn + n0;
    const float* nx0p = nxyz + ((size_t)(b * 3 + 0) * Nn + n0) * Ss + s;
    const float* nx1p = nxyz + ((size_t)(b * 3 + 1) * Nn + n0) * Ss + s;
    const float* nx2p = nxyz + ((size_t)(b * 3 + 2) * Nn + n0) * Ss + s;
    const float* xp   = xyz + (size_t)(b * 3) * Nn + n0;

    // q for all 8 points up front (full 32B/lane line use)
    float qv[PTS];
    {
        const float4 qA = ((const float4*)qrow)[0];
        const float4 qB = ((const float4*)qrow)[1];
        qv[0] = qA.x; qv[1] = qA.y; qv[2] = qA.z; qv[3] = qA.w;
        qv[4] = qB.x; qv[5] = qB.y; qv[6] = qB.z; qv[7] = qB.w;
    }

    // ---- depth-2 prefetch buffers (static-indexed under full unroll) ----
    float4 rnp[2][4];
    float rnx[2][3], rx[2][3];
#pragma unroll
    for (int i = 0; i < 2; ++i) {
        const float4* p4 = (const float4*)(nprow + (size_t)i * Ss);
        rnp[i][0] = p4[0]; rnp[i][1] = p4[1]; rnp[i][2] = p4[2]; rnp[i][3] = p4[3];
        rnx[i][0] = nx0p[(size_t)i * Ss];
        rnx[i][1] = nx1p[(size_t)i * Ss];
        rnx[i][2] = nx2p[(size_t)i * Ss];
        rx[i][0] = xp[i]; rx[i][1] = xp[Nn + i]; rx[i][2] = xp[2 * Nn + i];
    }

    float accv[PTS];

#pragma unroll
    for (int t = 0; t < PTS; ++t) {
        const int pb = t & 1;

        const float d0 = rx[pb][0] - rnx[pb][0];
        const float d1 = rx[pb][1] - rnx[pb][1];
        const float d2 = rx[pb][2] - rnx[pb][2];
        const float dn = sqrtf(d0 * d0 + d1 * d1 + d2 * d2);

        // ---- stage np row + q (scaled) into LDS ----
        float* row = &np_lds[w][lane * 17];
        row[0]  = rnp[pb][0].x; row[1]  = rnp[pb][0].y; row[2]  = rnp[pb][0].z; row[3]  = rnp[pb][0].w;
        row[4]  = rnp[pb][1].x; row[5]  = rnp[pb][1].y; row[6]  = rnp[pb][1].z; row[7]  = rnp[pb][1].w;
        row[8]  = rnp[pb][2].x; row[9]  = rnp[pb][2].y; row[10] = rnp[pb][2].z; row[11] = rnp[pb][2].w;
        row[12] = rnp[pb][3].x; row[13] = rnp[pb][3].y; row[14] = rnp[pb][3].z; row[15] = rnp[pb][3].w;
        q_lds[w][lane] = qv[t] * 0.125f;

        // ---- prefetch t+2 (2 bodies ahead ≈ 1.5-2K cycles > HBM latency) ----
        if (t + 2 < PTS) {
            const float4* p4 = (const float4*)(nprow + (size_t)(t + 2) * Ss);
            rnp[pb][0] = p4[0]; rnp[pb][1] = p4[1]; rnp[pb][2] = p4[2]; rnp[pb][3] = p4[3];
            rnx[pb][0] = nx0p[(size_t)(t + 2) * Ss];
            rnx[pb][1] = nx1p[(size_t)(t + 2) * Ss];
            rnx[pb][2] = nx2p[(size_t)(t + 2) * Ss];
            rx[pb][0] = xp[t + 2]; rx[pb][1] = xp[Nn + t + 2]; rx[pb][2] = xp[2 * Nn + t + 2];
        }

        WAVE_LDS_FENCE();   // fence 1: np + q staged

        // ---- qk[lane] = sum_o q[o]*Wk[o][lane]; q via LDS b128 broadcast ----
        const float4* q4 = (const float4*)q_lds[w];
        float a0 = 0.f, a1 = 0.f, a2 = 0.f, a3 = 0.f;
#pragma unroll
        for (int j2 = 0; j2 < 16; ++j2) {
            const float4 q = q4[j2];
            a0 = fmaf(q.x, wk[4 * j2 + 0], a0);
            a1 = fmaf(q.y, wk[4 * j2 + 1], a1);
            a2 = fmaf(q.z, wk[4 * j2 + 2], a2);
            a3 = fmaf(q.w, wk[4 * j2 + 3], a3);
        }
        const float qk = (a0 + a1) + (a2 + a3);
        qk_lds[w][lane] = qk;

        // pp sums (pure DPP) cover the qk_lds write latency before fence 2
        const float pp0 = sum64(qk * wp.x);
        const float pp1 = sum64(qk * wp.y);
        const float pp2 = sum64(qk * wp.z);
        const float pp3 = sum64(qk * wp.w);

        WAVE_LDS_FENCE();   // fence 2: only the 1-dword qk write outstanding

        // ---- logit: lane (g,s) reduces its 16-channel slice ----
        const float4* qk4 = (const float4*)qk_lds[w];
        float lp = 0.f;
#pragma unroll
        for (int j = 0; j < 4; ++j) {
            const float4 qq = qk4[g * 4 + j];
            const float* col = &np_lds[w][(16 * g + 4 * j) * 17 + s];
            lp = fmaf(qq.x, col[0], lp);
            lp = fmaf(qq.y, col[17], lp);
            lp = fmaf(qq.z, col[34], lp);
            lp = fmaf(qq.w, col[51], lp);
        }
        lp += __shfl_xor(lp, 16);
        lp += __shfl_xor(lp, 32);
        const float logit = lp + pp0 * d0 + pp1 * d1 + pp2 * d2 + pp3 * dn;

        // ---- softmax over s: pure DPP ----
        const float mx = rmax16(logit);
        const float e = __expf(logit - mx);
        const float se = rsum16(e);
        const float attn = e / se;

        // tail (tmp) channels of v, reduced over s
        const float vt0 = rsum16(attn * d0);
        const float vt1 = rsum16(attn * d1);
        const float vt2 = rsum16(attn * d2);

        // ---- vbar[lane] = sum_s attn[s]*np[lane][s]; attn via readlane ----
        float v0 = 0.f, v1 = 0.f, v2 = 0.f, v3 = 0.f;
#pragma unroll
        for (int j = 0; j < 4; ++j) {
            v0 = fmaf(lanebc(attn, 4 * j + 0), row[4 * j + 0], v0);
            v1 = fmaf(lanebc(attn, 4 * j + 1), row[4 * j + 1], v1);
            v2 = fmaf(lanebc(attn, 4 * j + 2), row[4 * j + 2], v2);
            v3 = fmaf(lanebc(attn, 4 * j + 3), row[4 * j + 3], v3);
        }
        const float vb = (v0 + v1) + (v2 + v3);

        // ---- out[lane] = Wv[lane,:64].vbar + Wv[lane,64:67].vtail; vb via readlane ----
        float c0 = 0.f, c1 = 0.f, c2 = 0.f, c3 = 0.f;
#pragma unroll
        for (int c4 = 0; c4 < 16; ++c4) {
            c0 = fmaf(lanebc(vb, 4 * c4 + 0), wv[4 * c4 + 0], c0);
            c1 = fmaf(lanebc(vb, 4 * c4 + 1), wv[4 * c4 + 1], c1);
            c2 = fmaf(lanebc(vb, 4 * c4 + 2), wv[4 * c4 + 2], c2);
            c3 = fmaf(lanebc(vb, 4 * c4 + 3), wv[4 * c4 + 3], c3);
        }
        float acc = (c0 + c1) + (c2 + c3);
        acc = fmaf(wv[64], vt0, acc);
        acc = fmaf(wv[65], vt1, acc);
        acc = fmaf(wv[66], vt2, acc);
        accv[t] = acc;
    }

    // ---- batched output: 32 contiguous bytes per lane, written once ----
    float* op = out + (size_t)(b * Cc + lane) * Nn + n0;
    ((float4*)op)[0] = make_float4(accv[0], accv[1], accv[2], accv[3]);
    ((float4*)op)[1] = make_float4(accv[4], accv[5], accv[6], accv[7]);
}

extern "C" void kernel_launch(void* const* d_in, const int* in_sizes, int n_in,
                              void* d_out, int out_size, void* d_ws, size_t ws_size,
                              hipStream_t stream) {
    const float* xyz    = (const float*)d_in[0];
    const float* nxyz   = (const float*)d_in[1];
    const float* points = (const float*)d_in[2];
    const float* npts   = (const float*)d_in[3];
    const float* Wk     = (const float*)d_in[4];
    const float* Wv     = (const float*)d_in[5];
    const float* Wp     = (const float*)d_in[6];
    // d_in[7] = bp — unused: constant-in-s logit shift cancels in softmax
    float* out = (float*)d_out;

    const int total_pts = 4 * Nn;                    // B*N = 65536
    const int blocks = total_pts / (WAVES * PTS);    // 2048

    hipLaunchKernelGGL(pt_attn_kernel, dim3(blocks), dim3(256), 0, stream,
                       xyz, nxyz, points, npts, Wk, Wv, Wp, out);
}